// Round 11
// baseline (279.698 us; speedup 1.0000x reference)
//
#include <hip/hip_runtime.h>
#include <math.h>

#define N_NODES 50000
#define N_EDGES 600000
#define DIM 128
#define HEADS 8
#define NBLK 196
#define DBINS 64
#define EBLK 2344   // (N_EDGES+255)/256
#define GBLK 1563   // (N_NODES+31)/32

typedef _Float16 v8h __attribute__((ext_vector_type(8)));
typedef _Float16 v2h __attribute__((ext_vector_type(2)));
typedef float v16f __attribute__((ext_vector_type(16)));

union v8h_u {
    v8h v;
    v2h p[4];
    _Float16 e[8];
};

__device__ __forceinline__ float dot2(v2h a, v2h b, float c) {
#if __has_builtin(__builtin_amdgcn_fdot2)
    return __builtin_amdgcn_fdot2(a, b, c, false);
#else
    return c + (float)a[0] * (float)b[0] + (float)a[1] * (float)b[1];
#endif
}

// ---------------- prep: zero counts/bins + W to MFMA-frag layout ----------------
__global__ __launch_bounds__(256) void prep_kernel(const float* __restrict__ Wq,
                                                   const float* __restrict__ Wk,
                                                   const float* __restrict__ Wv,
                                                   const float* __restrict__ Wo,
                                                   _Float16* __restrict__ Wfrag,
                                                   int* __restrict__ counts,
                                                   int* __restrict__ bins) {
    int i = blockIdx.x * 256 + threadIdx.x;
    if (i < N_NODES) counts[i] = 0;
    if (i < DBINS) bins[i] = 0;
    if (i < 16384) {
        int base = i * 4;
        int mat = i >> 12;
        int rem = i & 4095;
        int wave = rem >> 10;
        int kt = (rem >> 7) & 7;
        int lane = (rem >> 1) & 63;
        int jh = (rem & 1) * 4;
        const float* src = (mat == 0) ? Wq : (mat == 1) ? Wk : (mat == 2) ? Wv : Wo;
        int n = wave * 32 + (lane & 31);
        int kbase = kt * 16 + (lane >> 5) * 8 + jh;
        _Float16 o[4];
#pragma unroll
        for (int j = 0; j < 4; j++) o[j] = (_Float16)src[(kbase + j) * 128 + n];
        *(short4*)(Wfrag + base) = *(short4*)o;
    }
}

// ---------------- CSR build ----------------
__global__ __launch_bounds__(256) void hist_kernel(const int* __restrict__ rowi,
                                                   int* __restrict__ counts) {
    int e = blockIdx.x * 256 + threadIdx.x;
    if (e >= N_EDGES) return;
    atomicAdd(counts + rowi[e], 1);
}

__global__ __launch_bounds__(256) void reduce_bins(const int* __restrict__ counts,
                                                   int* __restrict__ partials,
                                                   int* __restrict__ bins) {
    __shared__ int lb[DBINS];
    __shared__ int ws4[4];
    if (threadIdx.x < DBINS) lb[threadIdx.x] = 0;
    __syncthreads();
    int idx = blockIdx.x * 256 + threadIdx.x;
    int v = (idx < N_NODES) ? counts[idx] : 0;
    if (idx < N_NODES) atomicAdd(lb + min(v, DBINS - 1), 1);
    int s = v;
#pragma unroll
    for (int off = 32; off > 0; off >>= 1) s += __shfl_down(s, off);
    if ((threadIdx.x & 63) == 0) ws4[threadIdx.x >> 6] = s;
    __syncthreads();
    if (threadIdx.x == 0) partials[blockIdx.x] = ws4[0] + ws4[1] + ws4[2] + ws4[3];
    if (threadIdx.x < DBINS) {
        int c = lb[threadIdx.x];
        if (c) atomicAdd(bins + threadIdx.x, c);
    }
}

__global__ __launch_bounds__(256) void scan2(const int* __restrict__ partials,
                                             int* __restrict__ offsets,
                                             const int* __restrict__ bins,
                                             int* __restrict__ bptr) {
    __shared__ int sh[256];
    int t = threadIdx.x;
    int v = (t < NBLK) ? partials[t] : 0;
    sh[t] = v;
    __syncthreads();
    for (int off = 1; off < 256; off <<= 1) {
        int a = sh[t];
        int b = (t >= off) ? sh[t - off] : 0;
        __syncthreads();
        sh[t] = a + b;
        __syncthreads();
    }
    if (t < NBLK) offsets[t] = sh[t] - v;  // exclusive
    if (t < 64) {
        int bv = bins[t];
        int bs = bv;
#pragma unroll
        for (int off = 1; off < 64; off <<= 1) {
            int u = __shfl_up(bs, off);
            if (t >= off) bs += u;
        }
        int total = __shfl(bs, 63);
        bptr[t] = total - bs;  // descending: bins > t come first
    }
}

__global__ __launch_bounds__(256) void block_scan(const int* __restrict__ counts,
                                                  const int* __restrict__ offsets,
                                                  int* __restrict__ start,
                                                  int* __restrict__ writeptr) {
    __shared__ int sh[256];
    int t = threadIdx.x;
    int idx = blockIdx.x * 256 + t;
    int v = (idx < N_NODES) ? counts[idx] : 0;
    sh[t] = v;
    __syncthreads();
    for (int off = 1; off < 256; off <<= 1) {
        int a = sh[t];
        int b = (t >= off) ? sh[t - off] : 0;
        __syncthreads();
        sh[t] = a + b;
        __syncthreads();
    }
    if (idx < N_NODES) {
        int s = offsets[blockIdx.x] + sh[t] - v;
        start[idx] = s;
        writeptr[idx] = s;
    }
}

__global__ __launch_bounds__(256) void scatter_all(const int* __restrict__ counts,
                                                   int* __restrict__ bptr,
                                                   int* __restrict__ perm,
                                                   const int* __restrict__ rowi,
                                                   const int* __restrict__ coli,
                                                   const float* __restrict__ eattr,
                                                   int* __restrict__ writeptr,
                                                   int2* __restrict__ ep) {
    if (blockIdx.x < NBLK) {
        __shared__ int lhist[DBINS];
        __shared__ int lbase[DBINS];
        if (threadIdx.x < DBINS) lhist[threadIdx.x] = 0;
        __syncthreads();
        int i = blockIdx.x * 256 + threadIdx.x;
        int b = -1, r = 0;
        if (i < N_NODES) {
            b = min(counts[i], DBINS - 1);
            r = atomicAdd(lhist + b, 1);
        }
        __syncthreads();
        if (threadIdx.x < DBINS) {
            int c = lhist[threadIdx.x];
            lbase[threadIdx.x] = c ? atomicAdd(bptr + threadIdx.x, c) : 0;
        }
        __syncthreads();
        if (b >= 0) perm[lbase[b] + r] = i;
    } else {
        int e = (blockIdx.x - NBLK) * 256 + threadIdx.x;
        if (e >= N_EDGES) return;
        int r = rowi[e];
        int pos = atomicAdd(writeptr + r, 1);
        ep[pos] = make_int2(coli[e], __float_as_int(eattr[e]));
    }
}

// ---------------- fused QKV GEMM: LDS-staged A (f32 x -> f16), 3 outputs ----------------
// block = one 32-row tile; wave w covers cols [w*32, w*32+32)
#define LDSTRIDE 132  // 32-row tile padded: 2-way LDS conflict max
__global__ __launch_bounds__(256) void gemm_qkv(const float* __restrict__ x,
                                                const _Float16* __restrict__ Wfrag,
                                                const float* __restrict__ bq,
                                                const float* __restrict__ bk,
                                                const float* __restrict__ bv,
                                                _Float16* __restrict__ Qh,
                                                _Float16* __restrict__ Kh,
                                                _Float16* __restrict__ Vh) {
    __shared__ _Float16 As[32 * LDSTRIDE];
    int tid = threadIdx.x;
    int wave = tid >> 6, lane = tid & 63;
    int m32 = lane & 31, quad = lane >> 5;
    int row0 = blockIdx.x * 32;

    // stage A tile: 32 rows x 128, f32 -> f16
    {
        int r = tid >> 3;
        int c0 = (tid & 7) * 16;
        int gr = row0 + r;
        bool valid = gr < N_NODES;
        const float4* src = (const float4*)(x + (size_t)gr * 128 + c0);
        _Float16* dst = As + r * LDSTRIDE + c0;
#pragma unroll
        for (int q = 0; q < 4; q++) {
            float4 v = valid ? src[q] : make_float4(0.f, 0.f, 0.f, 0.f);
            _Float16 o[4] = {(_Float16)v.x, (_Float16)v.y, (_Float16)v.z, (_Float16)v.w};
            *(short4*)(dst + q * 4) = *(short4*)o;
        }
    }
    __syncthreads();

    // A fragments (shared by all 3 matrices)
    v8h af[8];
#pragma unroll
    for (int kt = 0; kt < 8; kt++)
        af[kt] = *(const v8h*)(As + m32 * LDSTRIDE + kt * 16 + quad * 8);

    int col = wave * 32 + m32;
#pragma unroll
    for (int mat = 0; mat < 3; mat++) {
        const _Float16* wf = Wfrag + mat * 16384 + wave * 4096 + lane * 8;
        v16f acc;
#pragma unroll
        for (int r = 0; r < 16; r++) acc[r] = 0.0f;
#pragma unroll
        for (int kt = 0; kt < 8; kt++) {
            v8h bf = *(const v8h*)(wf + kt * 512);
            acc = __builtin_amdgcn_mfma_f32_32x32x16_f16(af[kt], bf, acc, 0, 0, 0);
        }
        const float* bias = (mat == 0) ? bq : (mat == 1) ? bk : bv;
        _Float16* C = (mat == 0) ? Qh : (mat == 1) ? Kh : Vh;
        float bias_v = bias[col];
#pragma unroll
        for (int r = 0; r < 16; r++) {
            int row = (r & 3) + 8 * (r >> 2) + 4 * quad;
            int gr = row0 + row;
            if (gr < N_NODES) C[(size_t)gr * 128 + col] = (_Float16)(acc[r] + bias_v);
        }
    }
}

// ---------------- output GEMM: LDS-staged f16 A, f32 out ----------------
__global__ __launch_bounds__(256) void gemm_out(const _Float16* __restrict__ Ah,
                                                const _Float16* __restrict__ Wfrag,
                                                const float* __restrict__ bo,
                                                float* __restrict__ C) {
    __shared__ _Float16 As[32 * LDSTRIDE];
    int tid = threadIdx.x;
    int wave = tid >> 6, lane = tid & 63;
    int m32 = lane & 31, quad = lane >> 5;
    int row0 = blockIdx.x * 32;

    {
        int r = tid >> 3;
        int c0 = (tid & 7) * 16;
        int gr = row0 + r;
        bool valid = gr < N_NODES;
        const v8h* src = (const v8h*)(Ah + (size_t)gr * 128 + c0);
        _Float16* dst = As + r * LDSTRIDE + c0;
        v8h z = {};
        *(v8h*)(dst) = valid ? src[0] : z;
        *(v8h*)(dst + 8) = valid ? src[1] : z;
    }
    __syncthreads();

    v8h af[8];
#pragma unroll
    for (int kt = 0; kt < 8; kt++)
        af[kt] = *(const v8h*)(As + m32 * LDSTRIDE + kt * 16 + quad * 8);

    int col = wave * 32 + m32;
    const _Float16* wf = Wfrag + 3 * 16384 + wave * 4096 + lane * 8;
    v16f acc;
#pragma unroll
    for (int r = 0; r < 16; r++) acc[r] = 0.0f;
#pragma unroll
    for (int kt = 0; kt < 8; kt++) {
        v8h bf = *(const v8h*)(wf + kt * 512);
        acc = __builtin_amdgcn_mfma_f32_32x32x16_f16(af[kt], bf, acc, 0, 0, 0);
    }
    float bias_v = bo[col];
#pragma unroll
    for (int r = 0; r < 16; r++) {
        int row = (r & 3) + 8 * (r >> 2) + 4 * quad;
        int gr = row0 + row;
        if (gr < N_NODES) C[(size_t)gr * 128 + col] = acc[r] + bias_v;
    }
}

// ---------------- fused attention: 16 lanes/node, 4-stream online softmax ----------------
// lane sub in [0,16): owns dims [sub*8, sub*8+8); head = sub>>1
__global__ __launch_bounds__(256, 6) void fused_attn(const _Float16* __restrict__ Q,
                                                     const _Float16* __restrict__ K,
                                                     const _Float16* __restrict__ V,
                                                     const int* __restrict__ start,
                                                     const int* __restrict__ counts,
                                                     const int* __restrict__ perm,
                                                     const int2* __restrict__ ep,
                                                     _Float16* __restrict__ Aout) {
    int t = blockIdx.x * 256 + threadIdx.x;
    int idx = t >> 4;
    int sub = t & 15;
    if (idx >= N_NODES) return;
    int n = perm[idx];

    v8h_u q;
    q.v = *(const v8h*)(Q + (size_t)n * 128 + sub * 8);

    int s0 = start[n];
    int e1 = s0 + counts[n];

    float m[4] = {-INFINITY, -INFINITY, -INFINITY, -INFINITY};
    float l[4] = {0.0f, 0.0f, 0.0f, 0.0f};
    float acc[4][8];
#pragma unroll
    for (int si = 0; si < 4; si++)
#pragma unroll
        for (int j = 0; j < 8; j++) acc[si][j] = 0.0f;

    auto step = [&](int si, int2 p, v8h_u k, v8h_u v) {
        float ea = __int_as_float(p.y);
        float dot = 0.0f;
#pragma unroll
        for (int j = 0; j < 4; j++) dot = dot2(q.p[j], k.p[j], dot);
        // reduce over the 2 lanes of this head
        dot += __shfl_xor(dot, 1);
        float s = dot * 0.25f + ea;
        // max over the node's 8 heads (16-lane group)
        float em = fmaxf(s, __shfl_xor(s, 2));
        em = fmaxf(em, __shfl_xor(em, 4));
        em = fmaxf(em, __shfl_xor(em, 8));
        float nm = fmaxf(m[si], em);
        float scale = __expf(m[si] - nm);
        float ex = __expf(s - nm);
        l[si] = l[si] * scale + ex;
#pragma unroll
        for (int j = 0; j < 8; j++)
            acc[si][j] = acc[si][j] * scale + ex * (float)v.e[j];
        m[si] = nm;
    };

    int i = s0;
    for (; i + 3 < e1; i += 4) {
        int2 p0 = ep[i], p1 = ep[i + 1], p2 = ep[i + 2], p3 = ep[i + 3];
        v8h_u k0, k1, k2, k3, v0, v1, v2, v3;
        k0.v = *(const v8h*)(K + (size_t)p0.x * 128 + sub * 8);
        k1.v = *(const v8h*)(K + (size_t)p1.x * 128 + sub * 8);
        k2.v = *(const v8h*)(K + (size_t)p2.x * 128 + sub * 8);
        k3.v = *(const v8h*)(K + (size_t)p3.x * 128 + sub * 8);
        v0.v = *(const v8h*)(V + (size_t)p0.x * 128 + sub * 8);
        v1.v = *(const v8h*)(V + (size_t)p1.x * 128 + sub * 8);
        v2.v = *(const v8h*)(V + (size_t)p2.x * 128 + sub * 8);
        v3.v = *(const v8h*)(V + (size_t)p3.x * 128 + sub * 8);
        step(0, p0, k0, v0);
        step(1, p1, k1, v1);
        step(2, p2, k2, v2);
        step(3, p3, k3, v3);
    }
    for (; i < e1; i++) {
        int2 p = ep[i];
        v8h_u k, v;
        k.v = *(const v8h*)(K + (size_t)p.x * 128 + sub * 8);
        v.v = *(const v8h*)(V + (size_t)p.x * 128 + sub * 8);
        step(0, p, k, v);
    }

    // merge 4 streams
    float mm = fmaxf(fmaxf(m[0], m[1]), fmaxf(m[2], m[3]));
    float w[4], ltot = 0.0f;
#pragma unroll
    for (int si = 0; si < 4; si++) {
        w[si] = (l[si] > 0.0f) ? __expf(m[si] - mm) : 0.0f;
        ltot += l[si] * w[si];
    }
    float inv = 1.0f / (ltot + 1e-8f);

    _Float16 tmp[8];
#pragma unroll
    for (int j = 0; j < 8; j++) {
        float o = (acc[0][j] * w[0] + acc[1][j] * w[1] + acc[2][j] * w[2] + acc[3][j] * w[3]) * inv;
        tmp[j] = (_Float16)o;
    }
    *(v8h*)(Aout + (size_t)n * 128 + sub * 8) = *(v8h*)tmp;
}

extern "C" void kernel_launch(void* const* d_in, const int* in_sizes, int n_in,
                              void* d_out, int out_size, void* d_ws, size_t ws_size,
                              hipStream_t stream) {
    const float* x = (const float*)d_in[0];
    const int* ei = (const int*)d_in[1];
    const float* eattr = (const float*)d_in[2];
    const float* Wq = (const float*)d_in[3];
    const float* bq = (const float*)d_in[4];
    const float* Wk = (const float*)d_in[5];
    const float* bk = (const float*)d_in[6];
    const float* Wv = (const float*)d_in[7];
    const float* bv = (const float*)d_in[8];
    const float* Wo = (const float*)d_in[9];
    const float* bo = (const float*)d_in[10];
    float* out = (float*)d_out;

    const int* rowi = ei;
    const int* coli = ei + N_EDGES;

    // workspace carve
    _Float16* Qh = (_Float16*)d_ws;
    _Float16* Kh = Qh + (size_t)N_NODES * DIM;
    _Float16* Vh = Kh + (size_t)N_NODES * DIM;
    _Float16* Ah = Vh + (size_t)N_NODES * DIM;
    _Float16* Wfrag = Ah + (size_t)N_NODES * DIM;  // 4*16384 shorts
    int* counts = (int*)(Wfrag + 4 * 16384);
    int* start = counts + N_NODES;
    int* writeptr = start + N_NODES;
    int* partials = writeptr + N_NODES;
    int* offsets = partials + 256;
    int* bins = offsets + 256;
    int* bptr = bins + 64;
    int* perm = bptr + 64;
    int2* ep = (int2*)(perm + N_NODES);

    // prep: zero counts/bins + W frag layout
    prep_kernel<<<NBLK, 256, 0, stream>>>(Wq, Wk, Wv, Wo, Wfrag, counts, bins);
    // CSR build + degree permutation (descending)
    hist_kernel<<<EBLK, 256, 0, stream>>>(rowi, counts);
    reduce_bins<<<NBLK, 256, 0, stream>>>(counts, partials, bins);
    scan2<<<1, 256, 0, stream>>>(partials, offsets, bins, bptr);
    block_scan<<<NBLK, 256, 0, stream>>>(counts, offsets, start, writeptr);
    scatter_all<<<NBLK + EBLK, 256, 0, stream>>>(counts, bptr, perm, rowi, coli, eattr,
                                                 writeptr, ep);

    // fused Q/K/V projection (LDS-staged A, f16 MFMA)
    gemm_qkv<<<GBLK, 256, 0, stream>>>(x, Wfrag, bq, bk, bv, Qh, Kh, Vh);

    // fused gather-attention (16 lanes per node)
    int ablocks = (N_NODES * 16 + 255) / 256;
    fused_attn<<<ablocks, 256, 0, stream>>>(Qh, Kh, Vh, start, counts, perm, ep, Ah);

    // output projection
    gemm_out<<<GBLK, 256, 0, stream>>>(Ah, Wfrag, bo, out);
}

// Round 12
// 238.337 us; speedup vs baseline: 1.1735x; 1.1735x over previous
//
#include <hip/hip_runtime.h>
#include <math.h>

#define N_NODES 50000
#define N_EDGES 600000
#define DIM 128
#define HEADS 8
#define NBLK 196
#define DBINS 64
#define EBLK 2344   // (N_EDGES+255)/256
#define GBLK 1563   // (N_NODES+31)/32

typedef _Float16 v8h __attribute__((ext_vector_type(8)));
typedef _Float16 v2h __attribute__((ext_vector_type(2)));
typedef float v16f __attribute__((ext_vector_type(16)));

union v8h_u {
    v8h v;
    v2h p[4];
    _Float16 e[8];
};

__device__ __forceinline__ float dot2(v2h a, v2h b, float c) {
#if __has_builtin(__builtin_amdgcn_fdot2)
    return __builtin_amdgcn_fdot2(a, b, c, false);
#else
    return c + (float)a[0] * (float)b[0] + (float)a[1] * (float)b[1];
#endif
}

// ---------------- prep: zero counts/bins + W to MFMA-frag layout ----------------
__global__ __launch_bounds__(256) void prep_kernel(const float* __restrict__ Wq,
                                                   const float* __restrict__ Wk,
                                                   const float* __restrict__ Wv,
                                                   const float* __restrict__ Wo,
                                                   _Float16* __restrict__ Wfrag,
                                                   int* __restrict__ counts,
                                                   int* __restrict__ bins) {
    int i = blockIdx.x * 256 + threadIdx.x;
    if (i < N_NODES) counts[i] = 0;
    if (i < DBINS) bins[i] = 0;
    if (i < 16384) {
        int base = i * 4;
        int mat = i >> 12;
        int rem = i & 4095;
        int wave = rem >> 10;
        int kt = (rem >> 7) & 7;
        int lane = (rem >> 1) & 63;
        int jh = (rem & 1) * 4;
        const float* src = (mat == 0) ? Wq : (mat == 1) ? Wk : (mat == 2) ? Wv : Wo;
        int n = wave * 32 + (lane & 31);
        int kbase = kt * 16 + (lane >> 5) * 8 + jh;
        _Float16 o[4];
#pragma unroll
        for (int j = 0; j < 4; j++) o[j] = (_Float16)src[(kbase + j) * 128 + n];
        *(short4*)(Wfrag + base) = *(short4*)o;
    }
}

// ---------------- CSR build ----------------
__global__ __launch_bounds__(256) void hist_kernel(const int* __restrict__ rowi,
                                                   int* __restrict__ counts) {
    int e = blockIdx.x * 256 + threadIdx.x;
    if (e >= N_EDGES) return;
    atomicAdd(counts + rowi[e], 1);
}

__global__ __launch_bounds__(256) void reduce_bins(const int* __restrict__ counts,
                                                   int* __restrict__ partials,
                                                   int* __restrict__ bins) {
    __shared__ int lb[DBINS];
    __shared__ int ws4[4];
    if (threadIdx.x < DBINS) lb[threadIdx.x] = 0;
    __syncthreads();
    int idx = blockIdx.x * 256 + threadIdx.x;
    int v = (idx < N_NODES) ? counts[idx] : 0;
    if (idx < N_NODES) atomicAdd(lb + min(v, DBINS - 1), 1);
    int s = v;
#pragma unroll
    for (int off = 32; off > 0; off >>= 1) s += __shfl_down(s, off);
    if ((threadIdx.x & 63) == 0) ws4[threadIdx.x >> 6] = s;
    __syncthreads();
    if (threadIdx.x == 0) partials[blockIdx.x] = ws4[0] + ws4[1] + ws4[2] + ws4[3];
    if (threadIdx.x < DBINS) {
        int c = lb[threadIdx.x];
        if (c) atomicAdd(bins + threadIdx.x, c);
    }
}

__global__ __launch_bounds__(256) void scan2(const int* __restrict__ partials,
                                             int* __restrict__ offsets,
                                             const int* __restrict__ bins,
                                             int* __restrict__ bptr) {
    __shared__ int sh[256];
    int t = threadIdx.x;
    int v = (t < NBLK) ? partials[t] : 0;
    sh[t] = v;
    __syncthreads();
    for (int off = 1; off < 256; off <<= 1) {
        int a = sh[t];
        int b = (t >= off) ? sh[t - off] : 0;
        __syncthreads();
        sh[t] = a + b;
        __syncthreads();
    }
    if (t < NBLK) offsets[t] = sh[t] - v;  // exclusive
    if (t < 64) {
        int bv = bins[t];
        int bs = bv;
#pragma unroll
        for (int off = 1; off < 64; off <<= 1) {
            int u = __shfl_up(bs, off);
            if (t >= off) bs += u;
        }
        int total = __shfl(bs, 63);
        bptr[t] = total - bs;  // descending: bins > t come first
    }
}

__global__ __launch_bounds__(256) void block_scan(const int* __restrict__ counts,
                                                  const int* __restrict__ offsets,
                                                  int* __restrict__ start,
                                                  int* __restrict__ writeptr) {
    __shared__ int sh[256];
    int t = threadIdx.x;
    int idx = blockIdx.x * 256 + t;
    int v = (idx < N_NODES) ? counts[idx] : 0;
    sh[t] = v;
    __syncthreads();
    for (int off = 1; off < 256; off <<= 1) {
        int a = sh[t];
        int b = (t >= off) ? sh[t - off] : 0;
        __syncthreads();
        sh[t] = a + b;
        __syncthreads();
    }
    if (idx < N_NODES) {
        int s = offsets[blockIdx.x] + sh[t] - v;
        start[idx] = s;
        writeptr[idx] = s;
    }
}

__global__ __launch_bounds__(256) void scatter_all(const int* __restrict__ counts,
                                                   int* __restrict__ bptr,
                                                   int* __restrict__ perm,
                                                   const int* __restrict__ rowi,
                                                   const int* __restrict__ coli,
                                                   const float* __restrict__ eattr,
                                                   int* __restrict__ writeptr,
                                                   int2* __restrict__ ep) {
    if (blockIdx.x < NBLK) {
        __shared__ int lhist[DBINS];
        __shared__ int lbase[DBINS];
        if (threadIdx.x < DBINS) lhist[threadIdx.x] = 0;
        __syncthreads();
        int i = blockIdx.x * 256 + threadIdx.x;
        int b = -1, r = 0;
        if (i < N_NODES) {
            b = min(counts[i], DBINS - 1);
            r = atomicAdd(lhist + b, 1);
        }
        __syncthreads();
        if (threadIdx.x < DBINS) {
            int c = lhist[threadIdx.x];
            lbase[threadIdx.x] = c ? atomicAdd(bptr + threadIdx.x, c) : 0;
        }
        __syncthreads();
        if (b >= 0) perm[lbase[b] + r] = i;
    } else {
        int e = (blockIdx.x - NBLK) * 256 + threadIdx.x;
        if (e >= N_EDGES) return;
        int r = rowi[e];
        int pos = atomicAdd(writeptr + r, 1);
        ep[pos] = make_int2(coli[e], __float_as_int(eattr[e]));
    }
}

// ---------------- fused QKV GEMM: LDS-staged A (f32 x -> f16), 3 outputs ----------------
#define LDSTRIDE 132
__global__ __launch_bounds__(256) void gemm_qkv(const float* __restrict__ x,
                                                const _Float16* __restrict__ Wfrag,
                                                const float* __restrict__ bq,
                                                const float* __restrict__ bk,
                                                const float* __restrict__ bv,
                                                _Float16* __restrict__ Qh,
                                                _Float16* __restrict__ Kh,
                                                _Float16* __restrict__ Vh) {
    __shared__ _Float16 As[32 * LDSTRIDE];
    int tid = threadIdx.x;
    int wave = tid >> 6, lane = tid & 63;
    int m32 = lane & 31, quad = lane >> 5;
    int row0 = blockIdx.x * 32;

    {
        int r = tid >> 3;
        int c0 = (tid & 7) * 16;
        int gr = row0 + r;
        bool valid = gr < N_NODES;
        const float4* src = (const float4*)(x + (size_t)gr * 128 + c0);
        _Float16* dst = As + r * LDSTRIDE + c0;
#pragma unroll
        for (int q = 0; q < 4; q++) {
            float4 v = valid ? src[q] : make_float4(0.f, 0.f, 0.f, 0.f);
            _Float16 o[4] = {(_Float16)v.x, (_Float16)v.y, (_Float16)v.z, (_Float16)v.w};
            *(short4*)(dst + q * 4) = *(short4*)o;
        }
    }
    __syncthreads();

    v8h af[8];
#pragma unroll
    for (int kt = 0; kt < 8; kt++)
        af[kt] = *(const v8h*)(As + m32 * LDSTRIDE + kt * 16 + quad * 8);

    int col = wave * 32 + m32;
#pragma unroll
    for (int mat = 0; mat < 3; mat++) {
        const _Float16* wf = Wfrag + mat * 16384 + wave * 4096 + lane * 8;
        v16f acc;
#pragma unroll
        for (int r = 0; r < 16; r++) acc[r] = 0.0f;
#pragma unroll
        for (int kt = 0; kt < 8; kt++) {
            v8h bf = *(const v8h*)(wf + kt * 512);
            acc = __builtin_amdgcn_mfma_f32_32x32x16_f16(af[kt], bf, acc, 0, 0, 0);
        }
        const float* bias = (mat == 0) ? bq : (mat == 1) ? bk : bv;
        _Float16* C = (mat == 0) ? Qh : (mat == 1) ? Kh : Vh;
        float bias_v = bias[col];
#pragma unroll
        for (int r = 0; r < 16; r++) {
            int row = (r & 3) + 8 * (r >> 2) + 4 * quad;
            int gr = row0 + row;
            if (gr < N_NODES) C[(size_t)gr * 128 + col] = (_Float16)(acc[r] + bias_v);
        }
    }
}

// ---------------- output GEMM: LDS-staged f16 A, f32 out ----------------
__global__ __launch_bounds__(256) void gemm_out(const _Float16* __restrict__ Ah,
                                                const _Float16* __restrict__ Wfrag,
                                                const float* __restrict__ bo,
                                                float* __restrict__ C) {
    __shared__ _Float16 As[32 * LDSTRIDE];
    int tid = threadIdx.x;
    int wave = tid >> 6, lane = tid & 63;
    int m32 = lane & 31, quad = lane >> 5;
    int row0 = blockIdx.x * 32;

    {
        int r = tid >> 3;
        int c0 = (tid & 7) * 16;
        int gr = row0 + r;
        bool valid = gr < N_NODES;
        const v8h* src = (const v8h*)(Ah + (size_t)gr * 128 + c0);
        _Float16* dst = As + r * LDSTRIDE + c0;
        v8h z = {};
        *(v8h*)(dst) = valid ? src[0] : z;
        *(v8h*)(dst + 8) = valid ? src[1] : z;
    }
    __syncthreads();

    v8h af[8];
#pragma unroll
    for (int kt = 0; kt < 8; kt++)
        af[kt] = *(const v8h*)(As + m32 * LDSTRIDE + kt * 16 + quad * 8);

    int col = wave * 32 + m32;
    const _Float16* wf = Wfrag + 3 * 16384 + wave * 4096 + lane * 8;
    v16f acc;
#pragma unroll
    for (int r = 0; r < 16; r++) acc[r] = 0.0f;
#pragma unroll
    for (int kt = 0; kt < 8; kt++) {
        v8h bf = *(const v8h*)(wf + kt * 512);
        acc = __builtin_amdgcn_mfma_f32_32x32x16_f16(af[kt], bf, acc, 0, 0, 0);
    }
    float bias_v = bo[col];
#pragma unroll
    for (int r = 0; r < 16; r++) {
        int row = (r & 3) + 8 * (r >> 2) + 4 * quad;
        int gr = row0 + row;
        if (gr < N_NODES) C[(size_t)gr * 128 + col] = acc[r] + bias_v;
    }
}

// ---------------- fused attention: 16 lanes/node, 2-stream online softmax (no spill) ----------------
// lane sub in [0,16): owns dims [sub*8, sub*8+8); head = sub>>1
__global__ __launch_bounds__(256) void fused_attn(const _Float16* __restrict__ Q,
                                                  const _Float16* __restrict__ K,
                                                  const _Float16* __restrict__ V,
                                                  const int* __restrict__ start,
                                                  const int* __restrict__ counts,
                                                  const int* __restrict__ perm,
                                                  const int2* __restrict__ ep,
                                                  _Float16* __restrict__ Aout) {
    int t = blockIdx.x * 256 + threadIdx.x;
    int idx = t >> 4;
    int sub = t & 15;
    if (idx >= N_NODES) return;
    int n = perm[idx];

    v8h_u q;
    q.v = *(const v8h*)(Q + (size_t)n * 128 + sub * 8);

    int s0 = start[n];
    int e1 = s0 + counts[n];

    float m0 = -INFINITY, l0 = 0.0f, m1 = -INFINITY, l1 = 0.0f;
    float accA[8], accB[8];
#pragma unroll
    for (int j = 0; j < 8; j++) { accA[j] = 0.0f; accB[j] = 0.0f; }

    auto step = [&](float& m, float& l, float* acc, int2 p, v8h_u k, v8h_u v) {
        float ea = __int_as_float(p.y);
        float dot = 0.0f;
#pragma unroll
        for (int j = 0; j < 4; j++) dot = dot2(q.p[j], k.p[j], dot);
        dot += __shfl_xor(dot, 1);  // 2 lanes per head
        float s = dot * 0.25f + ea;
        float em = fmaxf(s, __shfl_xor(s, 2));  // max over node's 8 heads
        em = fmaxf(em, __shfl_xor(em, 4));
        em = fmaxf(em, __shfl_xor(em, 8));
        float nm = fmaxf(m, em);
        float scale = __expf(m - nm);
        float ex = __expf(s - nm);
        l = l * scale + ex;
#pragma unroll
        for (int j = 0; j < 8; j++)
            acc[j] = acc[j] * scale + ex * (float)v.e[j];
        m = nm;
    };

    int i = s0;
    for (; i + 1 < e1; i += 2) {
        int2 p0 = ep[i], p1 = ep[i + 1];
        v8h_u k0, k1, v0, v1;
        k0.v = *(const v8h*)(K + (size_t)p0.x * 128 + sub * 8);
        k1.v = *(const v8h*)(K + (size_t)p1.x * 128 + sub * 8);
        v0.v = *(const v8h*)(V + (size_t)p0.x * 128 + sub * 8);
        v1.v = *(const v8h*)(V + (size_t)p1.x * 128 + sub * 8);
        step(m0, l0, accA, p0, k0, v0);
        step(m1, l1, accB, p1, k1, v1);
    }
    if (i < e1) {
        int2 p = ep[i];
        v8h_u k, v;
        k.v = *(const v8h*)(K + (size_t)p.x * 128 + sub * 8);
        v.v = *(const v8h*)(V + (size_t)p.x * 128 + sub * 8);
        step(m0, l0, accA, p, k, v);
    }

    // merge 2 streams
    float mm = fmaxf(m0, m1);
    float w0 = (l0 > 0.0f) ? __expf(m0 - mm) : 0.0f;
    float w1 = (l1 > 0.0f) ? __expf(m1 - mm) : 0.0f;
    float ltot = l0 * w0 + l1 * w1;
    float inv = 1.0f / (ltot + 1e-8f);

    _Float16 tmp[8];
#pragma unroll
    for (int j = 0; j < 8; j++)
        tmp[j] = (_Float16)((accA[j] * w0 + accB[j] * w1) * inv);
    *(v8h*)(Aout + (size_t)n * 128 + sub * 8) = *(v8h*)tmp;
}

extern "C" void kernel_launch(void* const* d_in, const int* in_sizes, int n_in,
                              void* d_out, int out_size, void* d_ws, size_t ws_size,
                              hipStream_t stream) {
    const float* x = (const float*)d_in[0];
    const int* ei = (const int*)d_in[1];
    const float* eattr = (const float*)d_in[2];
    const float* Wq = (const float*)d_in[3];
    const float* bq = (const float*)d_in[4];
    const float* Wk = (const float*)d_in[5];
    const float* bk = (const float*)d_in[6];
    const float* Wv = (const float*)d_in[7];
    const float* bv = (const float*)d_in[8];
    const float* Wo = (const float*)d_in[9];
    const float* bo = (const float*)d_in[10];
    float* out = (float*)d_out;

    const int* rowi = ei;
    const int* coli = ei + N_EDGES;

    // workspace carve
    _Float16* Qh = (_Float16*)d_ws;
    _Float16* Kh = Qh + (size_t)N_NODES * DIM;
    _Float16* Vh = Kh + (size_t)N_NODES * DIM;
    _Float16* Ah = Vh + (size_t)N_NODES * DIM;
    _Float16* Wfrag = Ah + (size_t)N_NODES * DIM;  // 4*16384 shorts
    int* counts = (int*)(Wfrag + 4 * 16384);
    int* start = counts + N_NODES;
    int* writeptr = start + N_NODES;
    int* partials = writeptr + N_NODES;
    int* offsets = partials + 256;
    int* bins = offsets + 256;
    int* bptr = bins + 64;
    int* perm = bptr + 64;
    int2* ep = (int2*)(perm + N_NODES);

    // prep: zero counts/bins + W frag layout
    prep_kernel<<<NBLK, 256, 0, stream>>>(Wq, Wk, Wv, Wo, Wfrag, counts, bins);
    // CSR build + degree permutation (descending)
    hist_kernel<<<EBLK, 256, 0, stream>>>(rowi, counts);
    reduce_bins<<<NBLK, 256, 0, stream>>>(counts, partials, bins);
    scan2<<<1, 256, 0, stream>>>(partials, offsets, bins, bptr);
    block_scan<<<NBLK, 256, 0, stream>>>(counts, offsets, start, writeptr);
    scatter_all<<<NBLK + EBLK, 256, 0, stream>>>(counts, bptr, perm, rowi, coli, eattr,
                                                 writeptr, ep);

    // fused Q/K/V projection (LDS-staged A, f16 MFMA)
    gemm_qkv<<<GBLK, 256, 0, stream>>>(x, Wfrag, bq, bk, bv, Qh, Kh, Vh);

    // fused gather-attention (16 lanes per node, 2 streams)
    int ablocks = (N_NODES * 16 + 255) / 256;
    fused_attn<<<ablocks, 256, 0, stream>>>(Qh, Kh, Vh, start, counts, perm, ep, Ah);

    // output projection
    gemm_out<<<GBLK, 256, 0, stream>>>(Ah, Wfrag, bo, out);
}